// Round 6
// baseline (36.137 us; speedup 1.0000x reference)
//
#include <hip/hip_runtime.h>
#include <math.h>

#define LOG2E 1.4426950408889634f
#define LN2   0.6931471805599453f

#if __has_builtin(__builtin_amdgcn_exp2f)
#define EXP2(x) __builtin_amdgcn_exp2f(x)
#else
#define EXP2(x) exp2f(x)
#endif
#if __has_builtin(__builtin_amdgcn_logf)
#define LOG2(x) __builtin_amdgcn_logf(x)
#else
#define LOG2(x) log2f(x)
#endif

// B=64, M=8, K=4, P=16, V=65536. ONE kernel: 64 blocks (1 batch each) x 1024 threads.
// 4 sub-blocks of 256 threads; sub-block u handles chunks (d0) u*4+it, it=0..3.
// Thread role in sub-block: c = t&255, i2 = c>>4 (d2), i3 = c&15 (d3); s-loop = d1.
// x via pairwise-table factorization (log2 domain):
//   xl = -(u2 + sum_a G[a][da] + sum_{a<b} P[ab][da][db]),  all tables pre-scaled
//   by LOG2E (P also by 2). Tables from 4x4 whitened Gram: ~1.5K entries/block.
// R4->R5 fix: pair map (01,02,03,12,13,23) had pb = pi-2 for pi=3,4 (gave 11,12);
// now an explicit lookup. Everything else identical to R4.

__global__ __launch_bounds__(1024) void k_all(
    const float* __restrict__ yr, const float* __restrict__ yi,
    const float* __restrict__ hr, const float* __restrict__ hi,
    const float* __restrict__ sr, const float* __restrict__ si,
    const float* __restrict__ vr, const float* __restrict__ vi,
    float* __restrict__ out)
{
    __shared__ float sL[8][8][2];
    __shared__ float sDinv[8];
    __shared__ float lyw[8][2];
    __shared__ float lhw[8][4][2];     // whitened h [m][k]
    __shared__ float ptr_[16], pti_[16];
    __shared__ float gdiag[4];         // g_aa (real)
    __shared__ float gr2[6], gi2[6];   // g_ab for pairs (01,02,03,12,13,23)
    __shared__ float wr_[4], wi_[4];   // w_a = sum_m conj(hw[m,a]) yw[m]
    __shared__ float u2s;              // LOG2E * |yw|^2
    __shared__ float G2[4][16];        // LOG2E * G_a[v]
    __shared__ float P2[6][16][16];    // 2*LOG2E * P_ab[va][vb]
    __shared__ float xbuf[4][16][256]; // [u][d1][c]
    __shared__ float pmax[4][256];
    __shared__ float cm[4][16][17];    // [u][s][cluster] maxes, reused for j1 sums
    __shared__ float m1b[4][16], m2b[4][16], m3b[4][16], s2b[4][16];
    __shared__ float part2[4][256], part3[4][256];
    __shared__ float pairs[48][17][2]; // [group][chunk(+pad)][{max,sum}]

    const int t = threadIdx.x;
    const int b = blockIdx.x;
    const int u = t >> 8, c = t & 255;
    const int i2 = c >> 4, i3 = c & 15;

    if (t < 16) { ptr_[t] = vr[(t << 12) * 4]; pti_[t] = vi[(t << 12) * 4]; }

    // ---------------- wave 0: whiten (validated R2/R3) ----------------
    if (t < 64) {
        const int lane = t;
        float ar_[8] = {}, ai_[8] = {}, Lr_[8] = {}, Li_[8] = {};
        if (lane < 8) {
#pragma unroll
            for (int k = 0; k < 8; ++k) {
                ar_[k] = sr[b * 64 + lane * 8 + k];
                ai_[k] = si[b * 64 + lane * 8 + k];
            }
        }
        float inv = 0.f;
#pragma unroll
        for (int j = 0; j < 8; ++j) {
            if (lane == j) {
                float d = ar_[j];
#pragma unroll
                for (int k = 0; k < 8; ++k) if (k < j) d -= Lr_[k]*Lr_[k] + Li_[k]*Li_[k];
                float ld = sqrtf(d);
                Lr_[j] = ld; Li_[j] = 0.f;
                inv = 1.f / ld;
                sDinv[j] = inv;
            }
            float invj = __shfl(inv, j);
            float cr = ar_[j], ci = ai_[j];
#pragma unroll
            for (int k = 0; k < 8; ++k) if (k < j) {
                float Ljrk = __shfl(Lr_[k], j);
                float Ljik = __shfl(Li_[k], j);
                cr -= Lr_[k]*Ljrk + Li_[k]*Ljik;
                ci -= Li_[k]*Ljrk - Lr_[k]*Ljik;
            }
            if (lane < 8 && lane > j) { Lr_[j] = cr * invj; Li_[j] = ci * invj; }
        }
        if (lane < 8) {
#pragma unroll
            for (int k = 0; k < 8; ++k) if (k <= lane) { sL[lane][k][0] = Lr_[k]; sL[lane][k][1] = Li_[k]; }
        }
        if (lane < 5) {
            float rr[8], ri[8], zr[8], zi[8];
            if (lane == 0) {
#pragma unroll
                for (int i = 0; i < 8; ++i) { rr[i] = yr[b*8+i]; ri[i] = yi[b*8+i]; }
            } else {
#pragma unroll
                for (int i = 0; i < 8; ++i) { rr[i] = hr[(b*8+i)*4 + (lane-1)]; ri[i] = hi[(b*8+i)*4 + (lane-1)]; }
            }
#pragma unroll
            for (int i = 0; i < 8; ++i) {
                float cr = rr[i], ci = ri[i];
#pragma unroll
                for (int k = 0; k < 8; ++k) if (k < i) {
                    cr -= sL[i][k][0]*zr[k] - sL[i][k][1]*zi[k];
                    ci -= sL[i][k][0]*zi[k] + sL[i][k][1]*zr[k];
                }
                float dv = sDinv[i];
                zr[i] = cr * dv; zi[i] = ci * dv;
                if (lane == 0) { lyw[i][0] = zr[i]; lyw[i][1] = zi[i]; }
                else           { lhw[i][lane-1][0] = zr[i]; lhw[i][lane-1][1] = zi[i]; }
            }
        }
    }
    __syncthreads();   // A

    // ---------------- Gram (15 tiny dot jobs) ----------------
    if (t < 15) {
        if (t < 4) {                       // g_aa
            float s = 0.f;
#pragma unroll
            for (int m = 0; m < 8; ++m) {
                float ar = lhw[m][t][0], ai = lhw[m][t][1];
                s = fmaf(ar, ar, fmaf(ai, ai, s));
            }
            gdiag[t] = s;
        } else if (t < 10) {               // g_ab, pairs (01,02,03,12,13,23)
            const int pi = t - 4;
            const int pa_tab[6] = {0, 0, 0, 1, 1, 2};
            const int pb_tab[6] = {1, 2, 3, 2, 3, 3};
            const int pa = pa_tab[pi];
            const int pb = pb_tab[pi];
            float srr = 0.f, sii = 0.f;
#pragma unroll
            for (int m = 0; m < 8; ++m) {
                float ar = lhw[m][pa][0], ai = lhw[m][pa][1];
                float br = lhw[m][pb][0], bi = lhw[m][pb][1];
                srr = fmaf(ar, br, fmaf(ai, bi, srr));
                sii = fmaf(ar, bi, fmaf(-ai, br, sii));
            }
            gr2[pi] = srr; gi2[pi] = sii;
        } else if (t < 14) {               // w_a
            const int a = t - 10;
            float swr = 0.f, swi = 0.f;
#pragma unroll
            for (int m = 0; m < 8; ++m) {
                float ar = lhw[m][a][0], ai = lhw[m][a][1];
                swr = fmaf(ar, lyw[m][0], fmaf(ai, lyw[m][1], swr));
                swi = fmaf(ar, lyw[m][1], fmaf(-ai, lyw[m][0], swi));
            }
            wr_[a] = swr; wi_[a] = swi;
        } else {                           // |yw|^2
            float s = 0.f;
#pragma unroll
            for (int m = 0; m < 8; ++m)
                s = fmaf(lyw[m][0], lyw[m][0], fmaf(lyw[m][1], lyw[m][1], s));
            u2s = LOG2E * s;
        }
    }
    __syncthreads();   // B

    // ---------------- tables ----------------
    if (t < 64) {
        const int a = t >> 4, v = t & 15;
        float pn2 = ptr_[v]*ptr_[v] + pti_[v]*pti_[v];
        G2[a][v] = LOG2E * (pn2 * gdiag[a] - 2.f*(ptr_[v]*wr_[a] + pti_[v]*wi_[a]));
    }
    for (int e = t; e < 1536; e += 1024) {
        const int tb = e >> 8, va = (e >> 4) & 15, vb = e & 15;
        float dotr = ptr_[va]*ptr_[vb] + pti_[va]*pti_[vb];
        float doti = ptr_[va]*pti_[vb] - pti_[va]*ptr_[vb];
        P2[tb][va][vb] = 2.f * LOG2E * (dotr*gr2[tb] - doti*gi2[tb]);
    }
    __syncthreads();   // C

    // ---------------- iteration-invariant per-thread pieces ----------------
    const float Kpart = u2s + G2[2][i2] + G2[3][i3] + P2[5][i2][i3];
    float Rp[16];
#pragma unroll
    for (int s = 0; s < 16; ++s)
        Rp[s] = G2[1][s] + P2[3][s][i2] + P2[4][s][i3];

    // ---------------- 4 chunk-iterations ----------------
    for (int it = 0; it < 4; ++it) {
        const int ch = u * 4 + it;
        const float Kit = Kpart + G2[0][ch] + P2[1][ch][i2] + P2[2][ch][i3];
        float xl[16];
        float vmA = -3.4e38f;
#pragma unroll
        for (int s = 0; s < 16; ++s) {
            float x = -(Kit + Rp[s] + P2[0][ch][s]);
            xl[s] = x;
            vmA = fmaxf(vmA, x);
            xbuf[u][s][c] = x;
        }
        pmax[u][c] = vmA;
        __syncthreads();   // D

        // 2a: row-cluster maxes (j1) + M2/M3
        {
            float m = -3.4e38f;
#pragma unroll
            for (int j = 0; j < 16; ++j) m = fmaxf(m, xbuf[u][i3][i2*16 + ((j + i3) & 15)]);
            cm[u][i3][i2] = m;
        }
        if (c < 16) {
            float m = -3.4e38f;
#pragma unroll
            for (int j = 0; j < 16; ++j) m = fmaxf(m, pmax[u][c*16 + ((j + c) & 15)]);
            m2b[u][c] = m;
        } else if (c < 32) {
            const int d = c - 16;
            float m = -3.4e38f;
#pragma unroll
            for (int j = 0; j < 16; ++j) m = fmaxf(m, pmax[u][d + 16*((j + d) & 15)]);
            m3b[u][d] = m;
        }
        __syncthreads();   // E

        // 2b: M1; shared-exp j2/j3 partials
        if (c < 16) {
            float m = -3.4e38f;
#pragma unroll
            for (int j = 0; j < 16; ++j) m = fmaxf(m, cm[u][c][j]);
            m1b[u][c] = m;
        }
        const float M2 = m2b[u][i2], M3 = m3b[u][i3];
        const float Mlo = fminf(M2, M3);
        float acc = 0.f;
#pragma unroll
        for (int s = 0; s < 16; ++s) acc += EXP2(xl[s] - Mlo);
        part2[u][c] = acc * EXP2(Mlo - M2);
        part3[u][c] = acc * EXP2(Mlo - M3);
        __syncthreads();   // F

        // 2c: j1 exp-sums; j2/j3 group sums -> pairs
        {
            const float M1 = m1b[u][i3];
            float ssum = 0.f;
#pragma unroll
            for (int j = 0; j < 16; ++j)
                ssum += EXP2(xbuf[u][i3][i2*16 + ((j + i3) & 15)] - M1);
            cm[u][i3][i2] = ssum;
        }
        if (c < 16) {
            float S2 = 0.f;
#pragma unroll
            for (int j = 0; j < 16; ++j) S2 += part2[u][c*16 + ((j + c) & 15)];
            s2b[u][c] = S2;
            pairs[16 + c][ch][0] = m2b[u][c];
            pairs[16 + c][ch][1] = S2;
        } else if (c < 32) {
            const int d = c - 16;
            float S3 = 0.f;
#pragma unroll
            for (int j = 0; j < 16; ++j) S3 += part3[u][d + 16*((j + d) & 15)];
            pairs[32 + d][ch][0] = m3b[u][d];
            pairs[32 + d][ch][1] = S3;
        }
        __syncthreads();   // G

        // 3: j1 pairs + j0 finalize
        if (c < 16) {
            float S1 = 0.f;
#pragma unroll
            for (int j = 0; j < 16; ++j) S1 += cm[u][c][j];
            pairs[c][ch][0] = m1b[u][c];
            pairs[c][ch][1] = S1;
        }
        if (c == 16) {
            float M0 = m2b[u][0];
#pragma unroll
            for (int i = 1; i < 16; ++i) M0 = fmaxf(M0, m2b[u][i]);
            float S0 = 0.f;
#pragma unroll
            for (int i = 0; i < 16; ++i) S0 += s2b[u][i] * EXP2(m2b[u][i] - M0);
            out[b*64 + ch] = LN2 * (LOG2(S0) + M0);
        }
        __syncthreads();   // H
    }

    // ---------------- final 48-group merge ----------------
    if (t < 48) {
        float M = pairs[t][0][0];
#pragma unroll
        for (int i = 1; i < 16; ++i) M = fmaxf(M, pairs[t][i][0]);
        float S = 0.f;
#pragma unroll
        for (int i = 0; i < 16; ++i) S += pairs[t][i][1] * EXP2(pairs[t][i][0] - M);
        out[b*64 + 16 + t] = LN2 * (LOG2(S) + M);
    }
}

extern "C" void kernel_launch(void* const* d_in, const int* in_sizes, int n_in,
                              void* d_out, int out_size, void* d_ws, size_t ws_size,
                              hipStream_t stream) {
    const float* yr = (const float*)d_in[0];
    const float* yi = (const float*)d_in[1];
    const float* hr = (const float*)d_in[2];
    const float* hi = (const float*)d_in[3];
    const float* sr = (const float*)d_in[4];
    const float* si = (const float*)d_in[5];
    const float* vr = (const float*)d_in[6];
    const float* vi = (const float*)d_in[7];
    float* out = (float*)d_out;
    hipLaunchKernelGGL(k_all, dim3(64), dim3(1024), 0, stream,
                       yr, yi, hr, hi, sr, si, vr, vi, out);
}